// Round 3
// baseline (859.182 us; speedup 1.0000x reference)
//
#include <hip/hip_runtime.h>
#include <hip/hip_fp16.h>

#define HH 128
#define WW 128
#define NPIX (HH*WW)
#define NB 8
#define NHEADS 6
#define HD 32
#define SCALE 0.17677669529663687f

typedef _Float16 h2 __attribute__((ext_vector_type(2)));
typedef _Float16 f16x8 __attribute__((ext_vector_type(8)));
typedef float f4 __attribute__((ext_vector_type(4)));

union V64B { f4 f[4]; h2 h[16]; _Float16 s[32]; };

#define LDK 40   // padded fp16 k-stride (80B rows: 16B-aligned b128 reads, ~2-way banks)

// ---------------- MFMA projection: C[pix][192] = A[pix][192k] * W[192k][192] ----------------
// grid (1024, 1, 3): z=0 q(from x, scaled), z=1 k, z=2 v.  512 threads = 8 waves (2m x 4n).
// BM=128 pixels, BN=192 (full), BK=32 x 6 steps. Wave tile: 64m x 48n.
// W is transposed fp32->fp16 into LDS on the fly (no precompute pass).
__global__ __launch_bounds__(512) void proj_mfma(
    const float* __restrict__ x, const float* __restrict__ ctx,
    const float* __restrict__ Wq, const float* __restrict__ Wk, const float* __restrict__ Wv,
    const float* __restrict__ bq, const float* __restrict__ bk, const float* __restrict__ bv,
    _Float16* __restrict__ qh, _Float16* __restrict__ kh, _Float16* __restrict__ vh)
{
    int z = blockIdx.z;
    const float* A = (z == 0) ? x : ctx;
    const float* Wt = (z == 0) ? Wq : (z == 1 ? Wk : Wv);
    const float* bias = (z == 0) ? bq : (z == 1 ? bk : bv);
    _Float16* outp = (z == 0) ? qh : (z == 1 ? kh : vh);
    float scale = (z == 0) ? SCALE : 1.f;

    __shared__ _Float16 As[128][LDK];
    __shared__ _Float16 Ws[192][LDK];

    int t = threadIdx.x;
    int m0 = blockIdx.x * 128;
    int b  = m0 / NPIX;
    int p0 = m0 % NPIX;
    const float* Ab = A + (size_t)b * 192 * NPIX + p0;

    int lane = t & 63;
    int wid  = t >> 6;
    int wm = wid & 1;        // 2 m-halves of 64
    int wn = wid >> 1;       // 4 n-quarters of 48
    int lr = lane & 15;
    int lk = lane >> 4;

    f4 acc[4][3] = {};

    for (int ks = 0; ks < 6; ks++) {
        int k0 = ks * 32;
        // stage A: 128 pix x 32 c (fp32 -> fp16 transpose). 4096 slots, 8/thread.
        #pragma unroll
        for (int i = 0; i < 8; i++) {
            int s = t + i * 512;
            int c = s >> 7, p = s & 127;
            As[p][c] = (_Float16)Ab[(size_t)(k0 + c) * NPIX + p];
        }
        // stage W^T: Ws[n][c] = W[k0+c][n], 6144 slots, 12/thread, coalesced in n.
        #pragma unroll
        for (int i = 0; i < 12; i++) {
            int s = t + i * 512;
            int c = s / 192, n = s - c * 192;
            Ws[n][c] = (_Float16)Wt[(size_t)(k0 + c) * 192 + n];
        }
        __syncthreads();

        f16x8 af[4], bf[3];
        #pragma unroll
        for (int mi = 0; mi < 4; mi++)
            af[mi] = *(const f16x8*)&As[wm * 64 + mi * 16 + lr][lk * 8];
        #pragma unroll
        for (int ni = 0; ni < 3; ni++)
            bf[ni] = *(const f16x8*)&Ws[wn * 48 + ni * 16 + lr][lk * 8];
        #pragma unroll
        for (int mi = 0; mi < 4; mi++)
            #pragma unroll
            for (int ni = 0; ni < 3; ni++)
                acc[mi][ni] = __builtin_amdgcn_mfma_f32_16x16x32_f16(af[mi], bf[ni], acc[mi][ni], 0, 0, 0);
        __syncthreads();
    }

    // epilogue: D[row=(lane>>4)*4+r][col=lane&15]
    #pragma unroll
    for (int ni = 0; ni < 3; ni++) {
        int n = wn * 48 + ni * 16 + lr;
        int g = n >> 5, d = n & 31;
        float bb = bias[n];
        _Float16* obase = outp + (size_t)(b * NHEADS + g) * NPIX * HD + d;
        #pragma unroll
        for (int mi = 0; mi < 4; mi++) {
            #pragma unroll
            for (int r = 0; r < 4; r++) {
                int p = p0 + wm * 64 + mi * 16 + lk * 4 + r;
                obase[(size_t)p * HD] = (_Float16)((acc[mi][ni][r] + bb) * scale);
            }
        }
    }
}

// ---------------- neighborhood attention body, one thread per pixel-head ----------------
template<int K>
__device__ __forceinline__ void na2d_body(
    const _Float16* __restrict__ qh, const _Float16* __restrict__ kh,
    const _Float16* __restrict__ vh, const float* __restrict__ rpb,
    _Float16* __restrict__ ah, int head_base, int bz, int tx, int ty)
{
    constexpr int NS = K / 2;
    constexpr int RW = 2 * K - 1;
    int hi = bz & 1;
    int b  = bz >> 1;
    int g  = head_base + hi;
    int w = tx * 16 + (threadIdx.x & 15);
    int h = ty * 16 + (threadIdx.x >> 4);

    size_t plane = (size_t)(b * NHEADS + g) * NPIX;

    V64B qv;
    {
        const f4* qp = (const f4*)(qh + (plane + (size_t)h * WW + w) * HD);
        #pragma unroll
        for (int i = 0; i < 4; i++) qv.f[i] = qp[i];
    }

    int r0 = h - NS; r0 = r0 < 0 ? 0 : r0; if (r0 > HH - K) r0 = HH - K;
    int c0 = w - NS; c0 = c0 < 0 ? 0 : c0; if (c0 > WW - K) c0 = WW - K;

    const float* rpb_b = rpb + (size_t)hi * RW * RW
                       + (size_t)(r0 - h + K - 1) * RW + (c0 - w + K - 1);

    float acc[32] = {};
    float l = 0.f;

    #pragma unroll 1
    for (int ki = 0; ki < K; ki++) {
        const _Float16* krow = kh + (plane + (size_t)(r0 + ki) * WW + c0) * HD;
        const _Float16* vrow = vh + (plane + (size_t)(r0 + ki) * WW + c0) * HD;
        const float* rprow = rpb_b + ki * RW;
        for (int kj = 0; kj < K; kj++) {
            V64B kv;
            const f4* kp = (const f4*)(krow + kj * HD);
            #pragma unroll
            for (int i = 0; i < 4; i++) kv.f[i] = kp[i];
            float s = rprow[kj];
            #pragma unroll
            for (int i = 0; i < 16; i++)
                s = __builtin_amdgcn_fdot2(qv.h[i], kv.h[i], s, false);
            float p = __expf(s);
            l += p;
            V64B vv;
            const f4* vp = (const f4*)(vrow + kj * HD);
            #pragma unroll
            for (int i = 0; i < 4; i++) vv.f[i] = vp[i];
            #pragma unroll
            for (int i = 0; i < 16; i++) {
                acc[2 * i]     += p * (float)vv.h[i][0];
                acc[2 * i + 1] += p * (float)vv.h[i][1];
            }
        }
    }

    float inv = 1.f / l;
    V64B ov;
    #pragma unroll
    for (int i = 0; i < 16; i++) {
        h2 t2;
        t2[0] = (_Float16)(acc[2 * i] * inv);
        t2[1] = (_Float16)(acc[2 * i + 1] * inv);
        ov.h[i] = t2;
    }
    f4* op = (f4*)(ah + (plane + (size_t)h * WW + w) * HD);
    #pragma unroll
    for (int i = 0; i < 4; i++) op[i] = ov.f[i];
}

// all three branches in one launch; XCD-contiguous block swizzle (3072 % 8 == 0 -> bijective)
__global__ __launch_bounds__(256) void na2d_all(
    const _Float16* __restrict__ qh, const _Float16* __restrict__ kh,
    const _Float16* __restrict__ vh,
    const float* __restrict__ rpb0, const float* __restrict__ rpb1,
    const float* __restrict__ rpb2, _Float16* __restrict__ ah)
{
    int bid = blockIdx.x;
    int swz = (bid & 7) * 384 + (bid >> 3);   // each XCD owns 384 consecutive logical blocks
    int branch = swz >> 10;                    // 1024 blocks per branch
    int rem = swz & 1023;
    int bz = rem >> 6;                         // (b, hi) plane pair
    int ty = (rem >> 3) & 7;
    int tx = rem & 7;
    if (branch == 0)      na2d_body<7>(qh, kh, vh, rpb0, ah, 0, bz, tx, ty);
    else if (branch == 1) na2d_body<9>(qh, kh, vh, rpb1, ah, 2, bz, tx, ty);
    else                  na2d_body<11>(qh, kh, vh, rpb2, ah, 4, bz, tx, ty);
}

// ---------------- MFMA output projection: out[b,co,pix] = attn[pix][192] @ Wo + bo ----------------
// grid 1024, 512 threads = 8 waves (2m x 4n). BM=128, BN=192, BK=32 (= one head) x 6.
// A-fragments load directly from global (layout is fragment-shaped); Wo staged to LDS fp16.
__global__ __launch_bounds__(512) void oproj_mfma(
    const _Float16* __restrict__ ah, const float* __restrict__ Wo,
    const float* __restrict__ bo, float* __restrict__ outp)
{
    __shared__ _Float16 Ws[192][LDK];

    int t = threadIdx.x;
    int m0 = blockIdx.x * 128;
    int b  = m0 / NPIX;
    int p0 = m0 % NPIX;

    int lane = t & 63;
    int wid  = t >> 6;
    int wm = wid & 1;
    int wn = wid >> 1;
    int lr = lane & 15;
    int lk = lane >> 4;

    f4 acc[4][3] = {};

    for (int ks = 0; ks < 6; ks++) {
        int k0 = ks * 32;
        #pragma unroll
        for (int i = 0; i < 12; i++) {
            int s = t + i * 512;
            int c = s / 192, n = s - c * 192;
            Ws[n][c] = (_Float16)Wo[(size_t)(k0 + c) * 192 + n];
        }
        __syncthreads();

        // A-fragment: pixel rows of head plane ks, 16B-aligned contiguous halves
        const _Float16* abase = ah + (size_t)(b * NHEADS + ks) * NPIX * HD;
        f16x8 af[4], bf[3];
        #pragma unroll
        for (int mi = 0; mi < 4; mi++)
            af[mi] = *(const f16x8*)&abase[(size_t)(p0 + wm * 64 + mi * 16 + lr) * HD + lk * 8];
        #pragma unroll
        for (int ni = 0; ni < 3; ni++)
            bf[ni] = *(const f16x8*)&Ws[wn * 48 + ni * 16 + lr][lk * 8];
        #pragma unroll
        for (int mi = 0; mi < 4; mi++)
            #pragma unroll
            for (int ni = 0; ni < 3; ni++)
                acc[mi][ni] = __builtin_amdgcn_mfma_f32_16x16x32_f16(af[mi], bf[ni], acc[mi][ni], 0, 0, 0);
        __syncthreads();
    }

    // epilogue: col = out channel n, rows = pixels -> f4 stores, 64B-coalesced per lk quad
    #pragma unroll
    for (int ni = 0; ni < 3; ni++) {
        int n = wn * 48 + ni * 16 + lr;
        float bb = bo[n];
        float* obase = outp + ((size_t)b * 192 + n) * NPIX + p0 + wm * 64;
        #pragma unroll
        for (int mi = 0; mi < 4; mi++) {
            f4 v = acc[mi][ni];
            v[0] += bb; v[1] += bb; v[2] += bb; v[3] += bb;
            *(f4*)&obase[mi * 16 + lk * 4] = v;
        }
    }
}

extern "C" void kernel_launch(void* const* d_in, const int* in_sizes, int n_in,
                              void* d_out, int out_size, void* d_ws, size_t ws_size,
                              hipStream_t stream) {
    const float* x    = (const float*)d_in[0];
    const float* ctx  = (const float*)d_in[1];
    const float* Wq   = (const float*)d_in[2];
    const float* bq   = (const float*)d_in[3];
    const float* Wk   = (const float*)d_in[4];
    const float* bk   = (const float*)d_in[5];
    const float* Wv   = (const float*)d_in[6];
    const float* bv   = (const float*)d_in[7];
    const float* Wo   = (const float*)d_in[8];
    const float* bo   = (const float*)d_in[9];
    const float* rpb0 = (const float*)d_in[10];
    const float* rpb1 = (const float*)d_in[11];
    const float* rpb2 = (const float*)d_in[12];

    size_t N = (size_t)NB * NHEADS * NPIX * HD;   // 25,165,824 elements
    _Float16* qh = (_Float16*)d_ws;
    _Float16* kh = qh + N;
    _Float16* vh = kh + N;
    _Float16* ah = vh + N;
    float* outp = (float*)d_out;

    proj_mfma<<<dim3(1024, 1, 3), 512, 0, stream>>>(x, ctx, Wq, Wk, Wv, bq, bk, bv, qh, kh, vh);
    na2d_all<<<3072, 256, 0, stream>>>(qh, kh, vh, rpb0, rpb1, rpb2, ah);
    oproj_mfma<<<1024, 512, 0, stream>>>(ah, Wo, bo, outp);
}

// Round 4
// 685.423 us; speedup vs baseline: 1.2535x; 1.2535x over previous
//
#include <hip/hip_runtime.h>
#include <hip/hip_fp16.h>

#define HH 128
#define WW 128
#define NPIX (HH*WW)
#define NB 8
#define NHEADS 6
#define HD 32
#define SCALE 0.17677669529663687f

typedef _Float16 h2 __attribute__((ext_vector_type(2)));
typedef _Float16 f16x8 __attribute__((ext_vector_type(8)));
typedef float f4 __attribute__((ext_vector_type(4)));

union V64B { f4 f[4]; h2 h[16]; _Float16 s[32]; };

#define LDK 40   // padded fp16 k-stride (80B rows: 16B-aligned b128 reads, ~2-way banks)

// ---------------- MFMA projection: C[pix][192] = A[pix][192k] * W[192k][192] ----------------
__global__ __launch_bounds__(512) void proj_mfma(
    const float* __restrict__ x, const float* __restrict__ ctx,
    const float* __restrict__ Wq, const float* __restrict__ Wk, const float* __restrict__ Wv,
    const float* __restrict__ bq, const float* __restrict__ bk, const float* __restrict__ bv,
    _Float16* __restrict__ qh, _Float16* __restrict__ kh, _Float16* __restrict__ vh)
{
    int z = blockIdx.z;
    const float* A = (z == 0) ? x : ctx;
    const float* Wt = (z == 0) ? Wq : (z == 1 ? Wk : Wv);
    const float* bias = (z == 0) ? bq : (z == 1 ? bk : bv);
    _Float16* outp = (z == 0) ? qh : (z == 1 ? kh : vh);
    float scale = (z == 0) ? SCALE : 1.f;

    __shared__ _Float16 As[128][LDK];
    __shared__ _Float16 Ws[192][LDK];

    int t = threadIdx.x;
    int m0 = blockIdx.x * 128;
    int b  = m0 / NPIX;
    int p0 = m0 % NPIX;
    const float* Ab = A + (size_t)b * 192 * NPIX + p0;

    int lane = t & 63;
    int wid  = t >> 6;
    int wm = wid & 1;
    int wn = wid >> 1;
    int lr = lane & 15;
    int lk = lane >> 4;

    f4 acc[4][3] = {};

    for (int ks = 0; ks < 6; ks++) {
        int k0 = ks * 32;
        #pragma unroll
        for (int i = 0; i < 8; i++) {
            int s = t + i * 512;
            int c = s >> 7, p = s & 127;
            As[p][c] = (_Float16)Ab[(size_t)(k0 + c) * NPIX + p];
        }
        #pragma unroll
        for (int i = 0; i < 12; i++) {
            int s = t + i * 512;
            int c = s / 192, n = s - c * 192;
            Ws[n][c] = (_Float16)Wt[(size_t)(k0 + c) * 192 + n];
        }
        __syncthreads();

        f16x8 af[4], bf[3];
        #pragma unroll
        for (int mi = 0; mi < 4; mi++)
            af[mi] = *(const f16x8*)&As[wm * 64 + mi * 16 + lr][lk * 8];
        #pragma unroll
        for (int ni = 0; ni < 3; ni++)
            bf[ni] = *(const f16x8*)&Ws[wn * 48 + ni * 16 + lr][lk * 8];
        #pragma unroll
        for (int mi = 0; mi < 4; mi++)
            #pragma unroll
            for (int ni = 0; ni < 3; ni++)
                acc[mi][ni] = __builtin_amdgcn_mfma_f32_16x16x32_f16(af[mi], bf[ni], acc[mi][ni], 0, 0, 0);
        __syncthreads();
    }

    #pragma unroll
    for (int ni = 0; ni < 3; ni++) {
        int n = wn * 48 + ni * 16 + lr;
        int g = n >> 5, d = n & 31;
        float bb = bias[n];
        _Float16* obase = outp + (size_t)(b * NHEADS + g) * NPIX * HD + d;
        #pragma unroll
        for (int mi = 0; mi < 4; mi++) {
            #pragma unroll
            for (int r = 0; r < 4; r++) {
                int p = p0 + wm * 64 + mi * 16 + lk * 4 + r;
                obase[(size_t)p * HD] = (_Float16)((acc[mi][ni][r] + bb) * scale);
            }
        }
    }
}

// ---------------- neighborhood attention body: one thread per pixel-head, pk-fp16 PV accum ----------------
template<int K>
__device__ __forceinline__ void na2d_body(
    const _Float16* __restrict__ qh, const _Float16* __restrict__ kh,
    const _Float16* __restrict__ vh, const float* __restrict__ rpb,
    _Float16* __restrict__ ah, int head_base, int bz, int tx, int ty)
{
    constexpr int NS = K / 2;
    constexpr int RW = 2 * K - 1;
    int hi = bz & 1;
    int b  = bz >> 1;
    int g  = head_base + hi;
    int w = tx * 16 + (threadIdx.x & 15);
    int h = ty * 16 + (threadIdx.x >> 4);

    size_t plane = (size_t)(b * NHEADS + g) * NPIX;

    V64B qv;
    {
        const f4* qp = (const f4*)(qh + (plane + (size_t)h * WW + w) * HD);
        #pragma unroll
        for (int i = 0; i < 4; i++) qv.f[i] = qp[i];
    }

    int r0 = h - NS; r0 = r0 < 0 ? 0 : r0; if (r0 > HH - K) r0 = HH - K;
    int c0 = w - NS; c0 = c0 < 0 ? 0 : c0; if (c0 > WW - K) c0 = WW - K;

    const float* rpb_b = rpb + (size_t)hi * RW * RW
                       + (size_t)(r0 - h + K - 1) * RW + (c0 - w + K - 1);

    h2 acc2[16] = {};
    float l = 0.f;

    #pragma unroll 1
    for (int ki = 0; ki < K; ki++) {
        const _Float16* krow = kh + (plane + (size_t)(r0 + ki) * WW + c0) * HD;
        const _Float16* vrow = vh + (plane + (size_t)(r0 + ki) * WW + c0) * HD;
        const float* rprow = rpb_b + ki * RW;
        for (int kj = 0; kj < K; kj++) {
            V64B kv;
            const f4* kp = (const f4*)(krow + kj * HD);
            #pragma unroll
            for (int i = 0; i < 4; i++) kv.f[i] = kp[i];
            float s = rprow[kj];
            #pragma unroll
            for (int i = 0; i < 16; i++)
                s = __builtin_amdgcn_fdot2(qv.h[i], kv.h[i], s, false);
            float p = __expf(s);
            l += p;
            _Float16 ph = (_Float16)p;
            h2 p2 = {ph, ph};
            V64B vv;
            const f4* vp = (const f4*)(vrow + kj * HD);
            #pragma unroll
            for (int i = 0; i < 4; i++) vv.f[i] = vp[i];
            #pragma unroll
            for (int i = 0; i < 16; i++)
                acc2[i] = acc2[i] + p2 * vv.h[i];
        }
    }

    _Float16 invh = (_Float16)(1.f / l);
    h2 inv2 = {invh, invh};
    V64B ov;
    #pragma unroll
    for (int i = 0; i < 16; i++) ov.h[i] = acc2[i] * inv2;
    f4* op = (f4*)(ah + (plane + (size_t)h * WW + w) * HD);
    #pragma unroll
    for (int i = 0; i < 4; i++) op[i] = ov.f[i];
}

// all three branches, one launch. Balanced XCD swizzle:
//   xcd = bid&7 owns 128 blocks of EVERY branch (2 planes each -> 4MB K+V, L2-resident),
//   and all XCDs run the same branch phase at the same time (no inter-XCD imbalance).
__global__ __launch_bounds__(256) void na2d_all(
    const _Float16* __restrict__ qh, const _Float16* __restrict__ kh,
    const _Float16* __restrict__ vh,
    const float* __restrict__ rpb0, const float* __restrict__ rpb1,
    const float* __restrict__ rpb2, _Float16* __restrict__ ah)
{
    int bid = blockIdx.x;
    int xcd = bid & 7;
    int i = bid >> 3;           // 0..383
    int phase = i >> 7;         // branch: 128 per XCD per branch
    int j = i & 127;
    int lb = xcd * 128 + j;     // local block within branch, 0..1023
    int bz = lb >> 6;           // (b, hi) plane pair
    int rem = lb & 63;
    int ty = rem >> 3, tx = rem & 7;
    if (phase == 0)      na2d_body<7>(qh, kh, vh, rpb0, ah, 0, bz, tx, ty);
    else if (phase == 1) na2d_body<9>(qh, kh, vh, rpb1, ah, 2, bz, tx, ty);
    else                 na2d_body<11>(qh, kh, vh, rpb2, ah, 4, bz, tx, ty);
}

// ---------------- MFMA output projection ----------------
__global__ __launch_bounds__(512) void oproj_mfma(
    const _Float16* __restrict__ ah, const float* __restrict__ Wo,
    const float* __restrict__ bo, float* __restrict__ outp)
{
    __shared__ _Float16 Ws[192][LDK];

    int t = threadIdx.x;
    int m0 = blockIdx.x * 128;
    int b  = m0 / NPIX;
    int p0 = m0 % NPIX;

    int lane = t & 63;
    int wid  = t >> 6;
    int wm = wid & 1;
    int wn = wid >> 1;
    int lr = lane & 15;
    int lk = lane >> 4;

    f4 acc[4][3] = {};

    for (int ks = 0; ks < 6; ks++) {
        int k0 = ks * 32;
        #pragma unroll
        for (int i = 0; i < 12; i++) {
            int s = t + i * 512;
            int c = s / 192, n = s - c * 192;
            Ws[n][c] = (_Float16)Wo[(size_t)(k0 + c) * 192 + n];
        }
        __syncthreads();

        const _Float16* abase = ah + (size_t)(b * NHEADS + ks) * NPIX * HD;
        f16x8 af[4], bf[3];
        #pragma unroll
        for (int mi = 0; mi < 4; mi++)
            af[mi] = *(const f16x8*)&abase[(size_t)(p0 + wm * 64 + mi * 16 + lr) * HD + lk * 8];
        #pragma unroll
        for (int ni = 0; ni < 3; ni++)
            bf[ni] = *(const f16x8*)&Ws[wn * 48 + ni * 16 + lr][lk * 8];
        #pragma unroll
        for (int mi = 0; mi < 4; mi++)
            #pragma unroll
            for (int ni = 0; ni < 3; ni++)
                acc[mi][ni] = __builtin_amdgcn_mfma_f32_16x16x32_f16(af[mi], bf[ni], acc[mi][ni], 0, 0, 0);
        __syncthreads();
    }

    #pragma unroll
    for (int ni = 0; ni < 3; ni++) {
        int n = wn * 48 + ni * 16 + lr;
        float bb = bo[n];
        float* obase = outp + ((size_t)b * 192 + n) * NPIX + p0 + wm * 64;
        #pragma unroll
        for (int mi = 0; mi < 4; mi++) {
            f4 v = acc[mi][ni];
            v[0] += bb; v[1] += bb; v[2] += bb; v[3] += bb;
            *(f4*)&obase[mi * 16 + lk * 4] = v;
        }
    }
}

extern "C" void kernel_launch(void* const* d_in, const int* in_sizes, int n_in,
                              void* d_out, int out_size, void* d_ws, size_t ws_size,
                              hipStream_t stream) {
    const float* x    = (const float*)d_in[0];
    const float* ctx  = (const float*)d_in[1];
    const float* Wq   = (const float*)d_in[2];
    const float* bq   = (const float*)d_in[3];
    const float* Wk   = (const float*)d_in[4];
    const float* bk   = (const float*)d_in[5];
    const float* Wv   = (const float*)d_in[6];
    const float* bv   = (const float*)d_in[7];
    const float* Wo   = (const float*)d_in[8];
    const float* bo   = (const float*)d_in[9];
    const float* rpb0 = (const float*)d_in[10];
    const float* rpb1 = (const float*)d_in[11];
    const float* rpb2 = (const float*)d_in[12];

    size_t N = (size_t)NB * NHEADS * NPIX * HD;   // 25,165,824 elements
    _Float16* qh = (_Float16*)d_ws;
    _Float16* kh = qh + N;
    _Float16* vh = kh + N;
    _Float16* ah = vh + N;
    float* outp = (float*)d_out;

    proj_mfma<<<dim3(1024, 1, 3), 512, 0, stream>>>(x, ctx, Wq, Wk, Wv, bq, bk, bv, qh, kh, vh);
    na2d_all<<<3072, 256, 0, stream>>>(qh, kh, vh, rpb0, rpb1, rpb2, ah);
    oproj_mfma<<<1024, 512, 0, stream>>>(ah, Wo, bo, outp);
}

// Round 6
// 317.407 us; speedup vs baseline: 2.7069x; 2.1594x over previous
//
#include <hip/hip_runtime.h>
#include <hip/hip_fp16.h>

#define HH 128
#define WW 128
#define NPIX (HH*WW)
#define NB 8
#define NHEADS 6
#define HD 32
#define SCALE 0.17677669529663687f

typedef _Float16 h2 __attribute__((ext_vector_type(2)));
typedef __fp16 g2 __attribute__((ext_vector_type(2)));
typedef _Float16 f16x8 __attribute__((ext_vector_type(8)));
typedef float f4 __attribute__((ext_vector_type(4)));

#define LDK 40   // padded fp16 k-stride (80B rows: 16B-aligned b128 reads, ~2-way banks)

// ---------------- MFMA projection: C[pix][192] = A[pix][192k] * W[192k][192] ----------------
__global__ __launch_bounds__(512) void proj_mfma(
    const float* __restrict__ x, const float* __restrict__ ctx,
    const float* __restrict__ Wq, const float* __restrict__ Wk, const float* __restrict__ Wv,
    const float* __restrict__ bq, const float* __restrict__ bk, const float* __restrict__ bv,
    _Float16* __restrict__ qh, _Float16* __restrict__ kh, _Float16* __restrict__ vh)
{
    int z = blockIdx.z;
    const float* A = (z == 0) ? x : ctx;
    const float* Wt = (z == 0) ? Wq : (z == 1 ? Wk : Wv);
    const float* bias = (z == 0) ? bq : (z == 1 ? bk : bv);
    _Float16* outp = (z == 0) ? qh : (z == 1 ? kh : vh);
    float scale = (z == 0) ? SCALE : 1.f;

    __shared__ _Float16 As[128][LDK];
    __shared__ _Float16 Ws[192][LDK];

    int t = threadIdx.x;
    int m0 = blockIdx.x * 128;
    int b  = m0 / NPIX;
    int p0 = m0 % NPIX;
    const float* Ab = A + (size_t)b * 192 * NPIX + p0;

    int lane = t & 63;
    int wid  = t >> 6;
    int wm = wid & 1;
    int wn = wid >> 1;
    int lr = lane & 15;
    int lk = lane >> 4;

    f4 acc[4][3] = {};

    for (int ks = 0; ks < 6; ks++) {
        int k0 = ks * 32;
        #pragma unroll
        for (int i = 0; i < 8; i++) {
            int s = t + i * 512;
            int c = s >> 7, p = s & 127;
            As[p][c] = (_Float16)Ab[(size_t)(k0 + c) * NPIX + p];
        }
        #pragma unroll
        for (int i = 0; i < 12; i++) {
            int s = t + i * 512;
            int c = s / 192, n = s - c * 192;
            Ws[n][c] = (_Float16)Wt[(size_t)(k0 + c) * 192 + n];
        }
        __syncthreads();

        f16x8 af[4], bf[3];
        #pragma unroll
        for (int mi = 0; mi < 4; mi++)
            af[mi] = *(const f16x8*)&As[wm * 64 + mi * 16 + lr][lk * 8];
        #pragma unroll
        for (int ni = 0; ni < 3; ni++)
            bf[ni] = *(const f16x8*)&Ws[wn * 48 + ni * 16 + lr][lk * 8];
        #pragma unroll
        for (int mi = 0; mi < 4; mi++)
            #pragma unroll
            for (int ni = 0; ni < 3; ni++)
                acc[mi][ni] = __builtin_amdgcn_mfma_f32_16x16x32_f16(af[mi], bf[ni], acc[mi][ni], 0, 0, 0);
        __syncthreads();
    }

    #pragma unroll
    for (int ni = 0; ni < 3; ni++) {
        int n = wn * 48 + ni * 16 + lr;
        int g = n >> 5, d = n & 31;
        float bb = bias[n];
        _Float16* obase = outp + (size_t)(b * NHEADS + g) * NPIX * HD + d;
        #pragma unroll
        for (int mi = 0; mi < 4; mi++) {
            #pragma unroll
            for (int r = 0; r < 4; r++) {
                int p = p0 + wm * 64 + mi * 16 + lk * 4 + r;
                obase[(size_t)p * HD] = (_Float16)((acc[mi][ni][r] + bb) * scale);
            }
        }
    }
}

// ---------------- MFMA neighborhood attention ----------------
// One block = 16x16 query tile of one (b, head) plane.
// LDS: Ks[26 rows][32 keys][40 fp16]  (natural [key][d], zero-padded keys)
//      Vt[26 rows][32 d][40 fp16]     (transposed, keys stored in pi-order)
//      rpbs[(2K-1)^2] f32
// QK^T: S^T = mfma(A=K16x32d, B=Q16x32d) -> lane holds query lq=lane&15, keys 4*lg+r (+16*chunk).
// pi-order: k_mfma slot 8g+s  <->  key  (s<4 ? 4g+s : 16+4g+(s-4)); lane's own scores ARE its
// PV A-fragment after cvt_pk (zero cross-lane movement). Vt staged with keys at pi^-1 position.
#define KS_ELE 33280            // 26*32*40 fp16
#define NA2D_SMEM 134912        // 2*66560 + 1764 rounded

template<int K>
__device__ __forceinline__ void na2d_tile(
    const _Float16* __restrict__ qh, const _Float16* __restrict__ kh,
    const _Float16* __restrict__ vh, const float* __restrict__ rpb,
    _Float16* __restrict__ ah, char* smem, int b, int g_head, int hi, int ty, int tx)
{
    constexpr int NS = K / 2;
    constexpr int RW = 2 * K - 1;
    _Float16* Ks = (_Float16*)smem;
    _Float16* Vt = Ks + KS_ELE;
    float* rpbs = (float*)(smem + 2 * KS_ELE * 2);

    int t = threadIdx.x;
    size_t plane = (size_t)(b * NHEADS + g_head) * NPIX;
    int h0 = ty * 16, w0 = tx * 16;
    int rmin = min(max(h0 - NS, 0), HH - K);
    int rtop = min(max(h0 + 15 - NS, 0), HH - K);
    int rows_n = rtop + K - rmin;               // <= 15+K <= 26
    int cwin0 = min(max(w0 - NS, 0), WW - K);
    int ctop = min(max(w0 + 15 - NS, 0), WW - K);
    int cols_n = ctop + K - cwin0;              // <= 26

    for (int i = t; i < RW * RW; i += 512) rpbs[i] = rpb[(size_t)hi * RW * RW + i];

    int ntask = rows_n * 128;                   // rows * 32 keys * 4 d-chunks
    for (int idx = t; idx < ntask; idx += 512) {
        int row = idx >> 7;
        int key = (idx >> 2) & 31;
        int dc  = idx & 3;
        f16x8 kv = {0,0,0,0,0,0,0,0};
        f16x8 vv = {0,0,0,0,0,0,0,0};
        if (key < cols_n) {
            size_t pix = plane + (size_t)(rmin + row) * WW + (cwin0 + key);
            kv = *(const f16x8*)&kh[pix * HD + dc * 8];
            vv = *(const f16x8*)&vh[pix * HD + dc * 8];
        }
        *(f16x8*)&Ks[row * 1280 + key * LDK + dc * 8] = kv;
        int m = 8 * ((key & 15) >> 2) + 4 * (key >> 4) + (key & 3);   // pi^-1(key)
        #pragma unroll
        for (int j = 0; j < 8; j++)
            Vt[row * 1280 + (dc * 8 + j) * LDK + m] = vv[j];
    }
    __syncthreads();

    int lane = t & 63, wid = t >> 6;
    int lq = lane & 15, lg = lane >> 4;
    int wq = w0 + lq;
    int c0q = min(max(wq - NS, 0), WW - K);
    int klo = c0q - cwin0;                       // valid key_local in [klo, klo+K)
    int shiftc = cwin0 - wq + K - 1;
    f4 zf4 = {0.f, 0.f, 0.f, 0.f};

    #pragma unroll 1
    for (int qi = 0; qi < 2; qi++) {
        int qr = wid * 2 + qi;
        int h = h0 + qr;
        int r0q = min(max(h - NS, 0), HH - K);
        int row_base = r0q - rmin;
        f16x8 qf = *(const f16x8*)&qh[(plane + (size_t)h * WW + w0 + lq) * HD + lg * 8];
        f4 acc0 = zf4, acc1 = zf4;
        float lsum = 0.f;

        #pragma unroll 1
        for (int ki = 0; ki < K; ki++) {
            int row = row_base + ki;
            const _Float16* kbase = &Ks[row * 1280 + lg * 8];
            f16x8 a0 = *(const f16x8*)&kbase[lq * LDK];
            f16x8 a1 = *(const f16x8*)&kbase[(16 + lq) * LDK];
            f4 s0 = __builtin_amdgcn_mfma_f32_16x16x32_f16(a0, qf, zf4, 0, 0, 0);
            f4 s1 = __builtin_amdgcn_mfma_f32_16x16x32_f16(a1, qf, zf4, 0, 0, 0);

            int rel_r = r0q + ki - h + K - 1;            // uniform per (qr,ki)
            const float* rrow = rpbs + rel_r * RW;
            float pf[2][4];
            #pragma unroll
            for (int c = 0; c < 2; c++) {
                #pragma unroll
                for (int r = 0; r < 4; r++) {
                    int key_local = c * 16 + 4 * lg + r;
                    int rc = key_local + shiftc;
                    rc = min(max(rc, 0), RW - 1);
                    float bias = rrow[rc];
                    bool valid = (unsigned)(key_local - klo) < (unsigned)K;
                    float sv = (c ? s1[r] : s0[r]) + bias;
                    float p = valid ? __expf(sv) : 0.f;
                    pf[c][r] = p;
                    lsum += p;
                }
            }
            union { g2 p[4]; f16x8 v; } P;
            P.p[0] = __builtin_amdgcn_cvt_pkrtz(pf[0][0], pf[0][1]);
            P.p[1] = __builtin_amdgcn_cvt_pkrtz(pf[0][2], pf[0][3]);
            P.p[2] = __builtin_amdgcn_cvt_pkrtz(pf[1][0], pf[1][1]);
            P.p[3] = __builtin_amdgcn_cvt_pkrtz(pf[1][2], pf[1][3]);

            const _Float16* vbase = &Vt[row * 1280 + lg * 8];
            f16x8 b0 = *(const f16x8*)&vbase[lq * LDK];
            f16x8 b1 = *(const f16x8*)&vbase[(16 + lq) * LDK];
            acc0 = __builtin_amdgcn_mfma_f32_16x16x32_f16(P.v, b0, acc0, 0, 0, 0);
            acc1 = __builtin_amdgcn_mfma_f32_16x16x32_f16(P.v, b1, acc1, 0, 0, 0);
        }

        lsum += __shfl_xor(lsum, 16);
        lsum += __shfl_xor(lsum, 32);
        float inv = 1.f / lsum;
        _Float16* obase = ah + (plane + (size_t)h * WW + w0) * HD;
        #pragma unroll
        for (int r = 0; r < 4; r++) {
            float ir = __shfl(inv, 4 * lg + r);
            obase[(4 * lg + r) * HD + lq]      = (_Float16)(acc0[r] * ir);
            obase[(4 * lg + r) * HD + lq + 16] = (_Float16)(acc1[r] * ir);
        }
    }
}

// 3072 blocks: balanced XCD swizzle — each XCD gets 128 blocks of every branch,
// all XCDs in the same branch phase simultaneously.
__global__ __launch_bounds__(512) void na2d_mfma(
    const _Float16* __restrict__ qh, const _Float16* __restrict__ kh,
    const _Float16* __restrict__ vh,
    const float* __restrict__ rpb0, const float* __restrict__ rpb1,
    const float* __restrict__ rpb2, _Float16* __restrict__ ah)
{
    extern __shared__ char smem[];
    int bid = blockIdx.x;
    int xcd = bid & 7;
    int i = bid >> 3;            // 0..383
    int phase = i >> 7;          // branch
    int j = i & 127;
    int lb = xcd * 128 + j;      // 0..1023 within branch
    int bz = lb >> 6;            // (b, hi)
    int tile = lb & 63;
    int b = bz >> 1, hi = bz & 1;
    int ty = tile >> 3, tx = tile & 7;
    if (phase == 0)      na2d_tile<7>(qh, kh, vh, rpb0, ah, smem, b, 0 + hi, hi, ty, tx);
    else if (phase == 1) na2d_tile<9>(qh, kh, vh, rpb1, ah, smem, b, 2 + hi, hi, ty, tx);
    else                 na2d_tile<11>(qh, kh, vh, rpb2, ah, smem, b, 4 + hi, hi, ty, tx);
}

// ---------------- MFMA output projection ----------------
__global__ __launch_bounds__(512) void oproj_mfma(
    const _Float16* __restrict__ ah, const float* __restrict__ Wo,
    const float* __restrict__ bo, float* __restrict__ outp)
{
    __shared__ _Float16 Ws[192][LDK];

    int t = threadIdx.x;
    int m0 = blockIdx.x * 128;
    int b  = m0 / NPIX;
    int p0 = m0 % NPIX;

    int lane = t & 63;
    int wid  = t >> 6;
    int wm = wid & 1;
    int wn = wid >> 1;
    int lr = lane & 15;
    int lk = lane >> 4;

    f4 acc[4][3] = {};

    for (int ks = 0; ks < 6; ks++) {
        int k0 = ks * 32;
        #pragma unroll
        for (int i = 0; i < 12; i++) {
            int s = t + i * 512;
            int c = s / 192, n = s - c * 192;
            Ws[n][c] = (_Float16)Wo[(size_t)(k0 + c) * 192 + n];
        }
        __syncthreads();

        const _Float16* abase = ah + (size_t)(b * NHEADS + ks) * NPIX * HD;
        f16x8 af[4], bf[3];
        #pragma unroll
        for (int mi = 0; mi < 4; mi++)
            af[mi] = *(const f16x8*)&abase[(size_t)(p0 + wm * 64 + mi * 16 + lr) * HD + lk * 8];
        #pragma unroll
        for (int ni = 0; ni < 3; ni++)
            bf[ni] = *(const f16x8*)&Ws[wn * 48 + ni * 16 + lr][lk * 8];
        #pragma unroll
        for (int mi = 0; mi < 4; mi++)
            #pragma unroll
            for (int ni = 0; ni < 3; ni++)
                acc[mi][ni] = __builtin_amdgcn_mfma_f32_16x16x32_f16(af[mi], bf[ni], acc[mi][ni], 0, 0, 0);
        __syncthreads();
    }

    #pragma unroll
    for (int ni = 0; ni < 3; ni++) {
        int n = wn * 48 + ni * 16 + lr;
        float bb = bo[n];
        float* obase = outp + ((size_t)b * 192 + n) * NPIX + p0 + wm * 64;
        #pragma unroll
        for (int mi = 0; mi < 4; mi++) {
            f4 v = acc[mi][ni];
            v[0] += bb; v[1] += bb; v[2] += bb; v[3] += bb;
            *(f4*)&obase[mi * 16 + lk * 4] = v;
        }
    }
}

extern "C" void kernel_launch(void* const* d_in, const int* in_sizes, int n_in,
                              void* d_out, int out_size, void* d_ws, size_t ws_size,
                              hipStream_t stream) {
    const float* x    = (const float*)d_in[0];
    const float* ctx  = (const float*)d_in[1];
    const float* Wq   = (const float*)d_in[2];
    const float* bq   = (const float*)d_in[3];
    const float* Wk   = (const float*)d_in[4];
    const float* bk   = (const float*)d_in[5];
    const float* Wv   = (const float*)d_in[6];
    const float* bv   = (const float*)d_in[7];
    const float* Wo   = (const float*)d_in[8];
    const float* bo   = (const float*)d_in[9];
    const float* rpb0 = (const float*)d_in[10];
    const float* rpb1 = (const float*)d_in[11];
    const float* rpb2 = (const float*)d_in[12];

    size_t N = (size_t)NB * NHEADS * NPIX * HD;   // 25,165,824 elements
    _Float16* qh = (_Float16*)d_ws;
    _Float16* kh = qh + N;
    _Float16* vh = kh + N;
    _Float16* ah = vh + N;
    float* outp = (float*)d_out;

    (void)hipFuncSetAttribute((const void*)na2d_mfma,
                              hipFuncAttributeMaxDynamicSharedMemorySize, NA2D_SMEM);

    proj_mfma<<<dim3(1024, 1, 3), 512, 0, stream>>>(x, ctx, Wq, Wk, Wv, bq, bk, bv, qh, kh, vh);
    na2d_mfma<<<3072, 512, NA2D_SMEM, stream>>>(qh, kh, vh, rpb0, rpb1, rpb2, ah);
    oproj_mfma<<<1024, 512, 0, stream>>>(ah, Wo, bo, outp);
}